// Round 8
// baseline (34.953 us; speedup 1.0000x reference)
//
#include <hip/hip_runtime.h>
#include <math.h>

#define NROWS 8192
#define NCLS  1000
#define NF4   250            // float4s per row (1000 floats)
#define LAMBDA_P 0.01f

#define RP_BLOCKS 512        // 4 waves/block -> 2048 waves, 4 rows/wave, pipelined
#define WAVES_TOT (RP_BLOCKS * 4)            // 2048
#define PEN_BLOCKS 32

typedef float f32x4 __attribute__((ext_vector_type(4)));

// ws layout (R3-proven):
//   ce_part f32[2048] @ 0      (8192 B)  one entry per row-pass WAVE
//   ce_sub  f32[32]   @ 8192
//   pen_sub f32[32]   @ 8320
//   counter int       @ 8448
//   truth   u8[8192]  @ 8704
// total 16896 B

__device__ __forceinline__ void load_row(f32x4* dst, const f32x4* base, int r, int lane) {
    const f32x4 ninf = { -INFINITY, -INFINITY, -INFINITY, -INFINITY };
    const f32x4* rp = base + (size_t)r * NF4;
#pragma unroll
    for (int k = 0; k < 4; ++k) {
        const int idx = lane + (k << 6);
        dst[k] = (idx < NF4) ? rp[idx] : ninf;
    }
}

// Full-wave reduce for one row held in v[4]. Returns CE (valid in all lanes);
// lane 0 writes truth[r]. Unstabilized sum: |logit| <= ~6 for N(0,1) inputs
// -> exp() in [2e-3, 4e2], fp32-safe; log(sum(exp(x))) == stabilized lse.
__device__ __forceinline__ float compute_row(const f32x4* v, int r, int lab,
                                             int lane, unsigned char* truth) {
    float m = -INFINITY; int mi = 0x7fffffff;
    float se = 0.0f;
#pragma unroll
    for (int k = 0; k < 4; ++k) {
        const int b4 = (lane + (k << 6)) << 2;
#pragma unroll
        for (int j = 0; j < 4; ++j) {
            const float a = v[k][j];
            se += __expf(a);                 // exp(-inf) = 0 for padded slots
            if (a > m) { m = a; mi = b4 + j; }
        }
    }
#pragma unroll
    for (int off = 32; off > 0; off >>= 1) {
        const float om = __shfl_xor(m, off, 64);
        const int   oi = __shfl_xor(mi, off, 64);
        se += __shfl_xor(se, off, 64);
        if (om > m || (om == m && oi < mi)) { m = om; mi = oi; }
    }

    // x[label] via owning-lane broadcast (wave-uniform selectors)
    const int lab4  = lab >> 2;
    const int lk    = lab4 >> 6;
    const int llane = lab4 & 63;
    const int lc    = lab & 3;
    f32x4 vv = v[0];
    if (lk == 1) vv = v[1];
    if (lk == 2) vv = v[2];
    if (lk == 3) vv = v[3];
    float xs = vv[0];
    if (lc == 1) xs = vv[1];
    if (lc == 2) xs = vv[2];
    if (lc == 3) xs = vv[3];
    const float xl = __shfl(xs, llane, 64);

    if (lane == 0) truth[r] = (mi == lab) ? 1u : 0u;
    return logf(se) - xl;
}

__global__ __launch_bounds__(256) void row_pass_k(const float* __restrict__ outputs,
                                                  const int* __restrict__ labels,
                                                  float* __restrict__ ce_part,
                                                  unsigned char* __restrict__ truth,
                                                  int* __restrict__ counter) {
    const int t    = threadIdx.x;
    const int lane = t & 63;
    const int wid  = t >> 6;
    const int gw   = blockIdx.x * 4 + wid;     // global wave id, 0..2047
    if (blockIdx.x == 0 && t == 0) *counter = 0;   // reset for penalty_fin combine

    const f32x4* base = reinterpret_cast<const f32x4*>(outputs);

    // rows r(i) = gw + i*2048, i = 0..3; labels are wave-uniform loads
    const int r0 = gw;
    const int r1 = gw + WAVES_TOT;
    const int r2 = gw + 2 * WAVES_TOT;
    const int r3 = gw + 3 * WAVES_TOT;
    const int lab0 = labels[r0];
    const int lab1 = labels[r1];
    const int lab2 = labels[r2];
    const int lab3 = labels[r3];

    // 2-deep software pipeline, static A/B register double-buffer:
    // next row's 4 KB of loads is in flight while current row reduces.
    f32x4 vA[4], vB[4];
    load_row(vA, base, r0, lane);
    load_row(vB, base, r1, lane);
    float ce = compute_row(vA, r0, lab0, lane, truth);
    load_row(vA, base, r2, lane);
    ce += compute_row(vB, r1, lab1, lane, truth);
    load_row(vB, base, r3, lane);
    ce += compute_row(vA, r2, lab2, lane, truth);
    ce += compute_row(vB, r3, lab3, lane, truth);

    if (lane == 0) ce_part[gw] = ce;           // one entry per wave, no LDS
}

// Penalty + final combine — byte-identical to R3's proven version.
// Sparsity: only K ~ N/1000 rows are "correct"; each block compacts the
// ordered correct-confidence list, then each thread handles one i with a
// K-length inner loop. Last block (counter protocol) combines and writes out.
__global__ __launch_bounds__(256) void penalty_fin_k(const float* __restrict__ conf,
                                                     const unsigned char* __restrict__ truth,
                                                     const float* __restrict__ ce_part,
                                                     float* __restrict__ ce_sub,
                                                     float* __restrict__ pen_sub,
                                                     int* __restrict__ counter,
                                                     float* __restrict__ out) {
    __shared__ float cconf[NROWS];     // worst-case compact list (32 KB)
    __shared__ int   wsum[4];
    __shared__ float sred[4];
    __shared__ float cred[1];
    __shared__ int   sK;
    __shared__ int   isLast;

    const int t    = threadIdx.x;
    const int lane = t & 63;
    const int wid  = t >> 6;
    const int b    = blockIdx.x;

    // deterministic compaction of correct set (each block redundantly);
    // thread t scans truth[t*32 .. t*32+32)
    const uint* tru32 = reinterpret_cast<const uint*>(truth);
    uint words[8];
#pragma unroll
    for (int q = 0; q < 8; ++q) words[q] = tru32[t * 8 + q];
    int cnt = 0;
#pragma unroll
    for (int q = 0; q < 8; ++q) {
        uint w = words[q];
        cnt += (w & 0xffu ? 1 : 0) + ((w >> 8) & 0xffu ? 1 : 0)
             + ((w >> 16) & 0xffu ? 1 : 0) + ((w >> 24) & 0xffu ? 1 : 0);
    }
    int inc = cnt;
#pragma unroll
    for (int d = 1; d < 64; d <<= 1) {
        int n = __shfl_up(inc, d, 64);
        if (lane >= d) inc += n;
    }
    if (lane == 63) wsum[wid] = inc;
    __syncthreads();
    int woff = 0;
    for (int w = 0; w < wid; ++w) woff += wsum[w];
    int slot = woff + inc - cnt;           // exclusive prefix
    if (t == 255) sK = woff + inc;
#pragma unroll
    for (int q = 0; q < 8; ++q) {
        uint w = words[q];
#pragma unroll
        for (int byte = 0; byte < 4; ++byte) {
            if ((w >> (byte * 8)) & 0xffu) {
                cconf[slot++] = conf[t * 32 + q * 4 + byte];
            }
        }
    }
    __syncthreads();
    const int K = sK;

    // one i per thread, K-length inner loop
    const int i = b * 256 + t;
    const float ci = conf[i];
    float acc = 0.0f;
    if (!truth[i]) {
        for (int s = 0; s < K; ++s) {
            const float d = ci - cconf[s];
            if (d > 0.0f) acc += d * d;
        }
    }
#pragma unroll
    for (int off = 32; off > 0; off >>= 1) acc += __shfl_xor(acc, off, 64);
    if (lane == 0) sred[wid] = acc;

    // this block's ce_part slice (64 entries, wave 0)
    float ce = (t < 64) ? ce_part[b * 64 + t] : 0.0f;
    if (wid == 0) {
#pragma unroll
        for (int off = 32; off > 0; off >>= 1) ce += __shfl_xor(ce, off, 64);
        if (lane == 0) cred[0] = ce;
    }
    __syncthreads();
    if (t == 0) {
        pen_sub[b] = sred[0] + sred[1] + sred[2] + sred[3];
        ce_sub[b]  = cred[0];
        __threadfence();
        int c = atomicAdd(counter, 1);
        isLast = (c == PEN_BLOCKS - 1) ? 1 : 0;
    }
    __syncthreads();

    if (isLast && wid == 0) {
        __threadfence();
        float cs = (lane < PEN_BLOCKS) ? ce_sub[lane]  : 0.0f;
        float ps = (lane < PEN_BLOCKS) ? pen_sub[lane] : 0.0f;
#pragma unroll
        for (int off = 32; off > 0; off >>= 1) {
            cs += __shfl_xor(cs, off, 64);
            ps += __shfl_xor(ps, off, 64);
        }
        if (lane == 0) out[0] = cs * (1.0f / (float)NROWS) + LAMBDA_P * ps;
    }
}

extern "C" void kernel_launch(void* const* d_in, const int* in_sizes, int n_in,
                              void* d_out, int out_size, void* d_ws, size_t ws_size,
                              hipStream_t stream) {
    const float* outputs = (const float*)d_in[0];
    const float* conf    = (const float*)d_in[1];
    const int*   labels  = (const int*)d_in[2];
    float* out = (float*)d_out;

    float*         ce_part = (float*)d_ws;
    float*         ce_sub  = (float*)((char*)d_ws + 8192);
    float*         pen_sub = (float*)((char*)d_ws + 8320);
    int*           counter = (int*)((char*)d_ws + 8448);
    unsigned char* truth   = (unsigned char*)((char*)d_ws + 8704);

    row_pass_k<<<RP_BLOCKS, 256, 0, stream>>>(outputs, labels, ce_part, truth, counter);
    penalty_fin_k<<<PEN_BLOCKS, 256, 0, stream>>>(conf, truth, ce_part,
                                                  ce_sub, pen_sub, counter, out);
}

// Round 9
// 30.937 us; speedup vs baseline: 1.1298x; 1.1298x over previous
//
#include <hip/hip_runtime.h>
#include <math.h>

#define NROWS 8192
#define NCLS  1000
#define NF4   250            // float4s per row (1000 floats)
#define LAMBDA_P 0.01f

#define CE_BLOCKS (NROWS / 4)   // 2048 blocks, 4 waves/block, 1 row/wave
#define PEN_BLOCKS 32           // 256 threads each -> 8192 threads, 1 i per thread

typedef float f32x4 __attribute__((ext_vector_type(4)));

// ws layout (R3-proven):
//   ce_part  float[2048]  @ 0      (8192 B)
//   ce_sub   float[32]    @ 8192
//   pen_sub  float[32]    @ 8320
//   counter  int          @ 8448
//   truth    u8[8192]     @ 8704
// total 16896 B

__global__ __launch_bounds__(256) void row_pass_k(const float* __restrict__ outputs,
                                                  const int* __restrict__ labels,
                                                  float* __restrict__ ce_part,
                                                  unsigned char* __restrict__ truth,
                                                  int* __restrict__ counter) {
    __shared__ float sce[4];
    const int t    = threadIdx.x;
    const int lane = t & 63;
    const int wid  = t >> 6;
    const int r    = (blockIdx.x << 2) + wid;
    if (blockIdx.x == 0 && t == 0) *counter = 0;   // reset for fused finalize
    const f32x4* rp = reinterpret_cast<const f32x4*>(outputs) + (size_t)r * NF4;
    const f32x4 ninf = { -INFINITY, -INFINITY, -INFINITY, -INFINITY };

    // SINGLE CHANGE vs R3: non-temporal loads. Streaming single-use data;
    // no L2/L3 allocation -> no eviction of the harness fill's dirty lines
    // -> removes ~40 MB/replay of writeback traffic competing with reads.
    f32x4 v[4];
#pragma unroll
    for (int k = 0; k < 4; ++k) {
        const int idx = lane + (k << 6);
        v[k] = (idx < NF4) ? __builtin_nontemporal_load(rp + idx) : ninf;
    }
    const int lab = labels[r];

    float m = -INFINITY; int mi = 0x7fffffff;
#pragma unroll
    for (int k = 0; k < 4; ++k) {
        const int base = (lane + (k << 6)) << 2;
        if (v[k].x > m) { m = v[k].x; mi = base; }
        if (v[k].y > m) { m = v[k].y; mi = base + 1; }
        if (v[k].z > m) { m = v[k].z; mi = base + 2; }
        if (v[k].w > m) { m = v[k].w; mi = base + 3; }
    }
#pragma unroll
    for (int off = 32; off > 0; off >>= 1) {
        const float om  = __shfl_xor(m, off, 64);
        const int   omi = __shfl_xor(mi, off, 64);
        if (om > m || (om == m && omi < mi)) { m = om; mi = omi; }
    }

    const int lab4  = lab >> 2;
    const int lk    = lab4 >> 6;
    const int llane = lab4 & 63;
    const int lc    = lab & 3;
    f32x4 vv = v[0];
    if (lk == 1) vv = v[1];
    if (lk == 2) vv = v[2];
    if (lk == 3) vv = v[3];
    float xs = vv.x;
    if (lc == 1) xs = vv.y;
    if (lc == 2) xs = vv.z;
    if (lc == 3) xs = vv.w;
    const float xl = __shfl(xs, llane, 64);

    float se = 0.0f;
#pragma unroll
    for (int k = 0; k < 4; ++k) {
        se += __expf(v[k].x - m) + __expf(v[k].y - m)
            + __expf(v[k].z - m) + __expf(v[k].w - m);
    }
#pragma unroll
    for (int off = 32; off > 0; off >>= 1) se += __shfl_xor(se, off, 64);

    if (lane == 0) {
        sce[wid] = (m + logf(se)) - xl;
        truth[r] = (mi == lab) ? 1u : 0u;
    }
    __syncthreads();
    if (t == 0) ce_part[blockIdx.x] = sce[0] + sce[1] + sce[2] + sce[3];
}

// Penalty + final combine — byte-identical to R3's proven 25.8 µs version.
__global__ __launch_bounds__(256) void penalty_fin_k(const float* __restrict__ conf,
                                                     const unsigned char* __restrict__ truth,
                                                     const float* __restrict__ ce_part,
                                                     float* __restrict__ ce_sub,
                                                     float* __restrict__ pen_sub,
                                                     int* __restrict__ counter,
                                                     float* __restrict__ out) {
    __shared__ float cconf[NROWS];     // worst-case compact list (32 KB)
    __shared__ int   wsum[4];
    __shared__ float sred[4];
    __shared__ float cred[1];
    __shared__ int   sK;
    __shared__ int   isLast;

    const int t    = threadIdx.x;
    const int lane = t & 63;
    const int wid  = t >> 6;
    const int b    = blockIdx.x;

    // deterministic compaction of correct set (each block redundantly);
    // thread t scans truth[t*32 .. t*32+32)
    const uint* tru32 = reinterpret_cast<const uint*>(truth);
    uint words[8];
#pragma unroll
    for (int q = 0; q < 8; ++q) words[q] = tru32[t * 8 + q];
    int cnt = 0;
#pragma unroll
    for (int q = 0; q < 8; ++q) {
        uint w = words[q];
        cnt += (w & 0xffu ? 1 : 0) + ((w >> 8) & 0xffu ? 1 : 0)
             + ((w >> 16) & 0xffu ? 1 : 0) + ((w >> 24) & 0xffu ? 1 : 0);
    }
    int inc = cnt;
#pragma unroll
    for (int d = 1; d < 64; d <<= 1) {
        int n = __shfl_up(inc, d, 64);
        if (lane >= d) inc += n;
    }
    if (lane == 63) wsum[wid] = inc;
    __syncthreads();
    int woff = 0;
    for (int w = 0; w < wid; ++w) woff += wsum[w];
    int slot = woff + inc - cnt;           // exclusive prefix
    if (t == 255) sK = woff + inc;
#pragma unroll
    for (int q = 0; q < 8; ++q) {
        uint w = words[q];
#pragma unroll
        for (int byte = 0; byte < 4; ++byte) {
            if ((w >> (byte * 8)) & 0xffu) {
                cconf[slot++] = conf[t * 32 + q * 4 + byte];
            }
        }
    }
    __syncthreads();
    const int K = sK;

    // one i per thread, K-length inner loop
    const int i = b * 256 + t;
    const float ci = conf[i];
    float acc = 0.0f;
    if (!truth[i]) {
        for (int s = 0; s < K; ++s) {
            const float d = ci - cconf[s];
            if (d > 0.0f) acc += d * d;
        }
    }
#pragma unroll
    for (int off = 32; off > 0; off >>= 1) acc += __shfl_xor(acc, off, 64);
    if (lane == 0) sred[wid] = acc;

    // this block's ce_part slice (64 entries)
    float ce = (t < 64) ? ce_part[b * 64 + t] : 0.0f;
    if (wid == 0) {
#pragma unroll
        for (int off = 32; off > 0; off >>= 1) ce += __shfl_xor(ce, off, 64);
        if (lane == 0) cred[0] = ce;
    }
    __syncthreads();
    if (t == 0) {
        pen_sub[b] = sred[0] + sred[1] + sred[2] + sred[3];
        ce_sub[b]  = cred[0];
        __threadfence();
        int c = atomicAdd(counter, 1);
        isLast = (c == PEN_BLOCKS - 1) ? 1 : 0;
    }
    __syncthreads();

    if (isLast && wid == 0) {
        __threadfence();
        float cs = (lane < PEN_BLOCKS) ? ce_sub[lane]  : 0.0f;
        float ps = (lane < PEN_BLOCKS) ? pen_sub[lane] : 0.0f;
#pragma unroll
        for (int off = 32; off > 0; off >>= 1) {
            cs += __shfl_xor(cs, off, 64);
            ps += __shfl_xor(ps, off, 64);
        }
        if (lane == 0) out[0] = cs * (1.0f / (float)NROWS) + LAMBDA_P * ps;
    }
}

extern "C" void kernel_launch(void* const* d_in, const int* in_sizes, int n_in,
                              void* d_out, int out_size, void* d_ws, size_t ws_size,
                              hipStream_t stream) {
    const float* outputs = (const float*)d_in[0];
    const float* conf    = (const float*)d_in[1];
    const int*   labels  = (const int*)d_in[2];
    float* out = (float*)d_out;

    float*         ce_part = (float*)d_ws;
    float*         ce_sub  = (float*)((char*)d_ws + 8192);
    float*         pen_sub = (float*)((char*)d_ws + 8320);
    int*           counter = (int*)((char*)d_ws + 8448);
    unsigned char* truth   = (unsigned char*)((char*)d_ws + 8704);

    row_pass_k<<<CE_BLOCKS, 256, 0, stream>>>(outputs, labels, ce_part, truth, counter);
    penalty_fin_k<<<PEN_BLOCKS, 256, 0, stream>>>(conf, truth, ce_part,
                                                  ce_sub, pen_sub, counter, out);
}

// Round 10
// 25.565 us; speedup vs baseline: 1.3672x; 1.2101x over previous
//
#include <hip/hip_runtime.h>
#include <math.h>

#define NROWS 8192
#define NCLS  1000
#define NF4   250            // float4s per row (1000 floats)
#define LAMBDA_P 0.01f

#define CE_BLOCKS (NROWS / 4)   // 2048 blocks, 4 waves/block, 1 row/wave
#define PEN_BLOCKS 32           // 256 threads each -> 8192 threads, 1 i per thread

// ws layout:
//   ce_part  float[2048]  @ 0      (8192 B)
//   ce_sub   float[32]    @ 8192
//   pen_sub  float[32]    @ 8320
//   counter  int          @ 8448
//   truth    u8[8192]     @ 8704
// total 16896 B

__global__ __launch_bounds__(256) void row_pass_k(const float* __restrict__ outputs,
                                                  const int* __restrict__ labels,
                                                  float* __restrict__ ce_part,
                                                  unsigned char* __restrict__ truth,
                                                  int* __restrict__ counter) {
    __shared__ float sce[4];
    const int t    = threadIdx.x;
    const int lane = t & 63;
    const int wid  = t >> 6;
    const int r    = (blockIdx.x << 2) + wid;
    if (blockIdx.x == 0 && t == 0) *counter = 0;   // reset for fused finalize
    const float4* rp = reinterpret_cast<const float4*>(outputs) + (size_t)r * NF4;

    float4 v[4];
#pragma unroll
    for (int k = 0; k < 4; ++k) {
        const int idx = lane + (k << 6);
        v[k] = (idx < NF4) ? rp[idx]
                           : make_float4(-INFINITY, -INFINITY, -INFINITY, -INFINITY);
    }
    const int lab = labels[r];

    float m = -INFINITY; int mi = 0x7fffffff;
#pragma unroll
    for (int k = 0; k < 4; ++k) {
        const int base = (lane + (k << 6)) << 2;
        if (v[k].x > m) { m = v[k].x; mi = base; }
        if (v[k].y > m) { m = v[k].y; mi = base + 1; }
        if (v[k].z > m) { m = v[k].z; mi = base + 2; }
        if (v[k].w > m) { m = v[k].w; mi = base + 3; }
    }
#pragma unroll
    for (int off = 32; off > 0; off >>= 1) {
        const float om  = __shfl_xor(m, off, 64);
        const int   omi = __shfl_xor(mi, off, 64);
        if (om > m || (om == m && omi < mi)) { m = om; mi = omi; }
    }

    const int lab4  = lab >> 2;
    const int lk    = lab4 >> 6;
    const int llane = lab4 & 63;
    const int lc    = lab & 3;
    float4 vv = v[0];
    if (lk == 1) vv = v[1];
    if (lk == 2) vv = v[2];
    if (lk == 3) vv = v[3];
    float xs = vv.x;
    if (lc == 1) xs = vv.y;
    if (lc == 2) xs = vv.z;
    if (lc == 3) xs = vv.w;
    const float xl = __shfl(xs, llane, 64);

    float se = 0.0f;
#pragma unroll
    for (int k = 0; k < 4; ++k) {
        se += __expf(v[k].x - m) + __expf(v[k].y - m)
            + __expf(v[k].z - m) + __expf(v[k].w - m);
    }
#pragma unroll
    for (int off = 32; off > 0; off >>= 1) se += __shfl_xor(se, off, 64);

    if (lane == 0) {
        sce[wid] = (m + logf(se)) - xl;
        truth[r] = (mi == lab) ? 1u : 0u;
    }
    __syncthreads();
    if (t == 0) ce_part[blockIdx.x] = sce[0] + sce[1] + sce[2] + sce[3];
}

// Fused penalty + final combine. Exploits sparsity: only K ~ N/1000 rows are
// "correct"; each block builds the ordered compact list of correct confidences
// (deterministic ascending-j order), then each thread does a K-length inner loop.
__global__ __launch_bounds__(256) void penalty_fin_k(const float* __restrict__ conf,
                                                     const unsigned char* __restrict__ truth,
                                                     const float* __restrict__ ce_part,
                                                     float* __restrict__ ce_sub,
                                                     float* __restrict__ pen_sub,
                                                     int* __restrict__ counter,
                                                     float* __restrict__ out) {
    __shared__ float cconf[NROWS];     // worst-case compact list (32 KB)
    __shared__ int   wsum[4];
    __shared__ float sred[4];
    __shared__ float cred[1];
    __shared__ int   sK;
    __shared__ int   isLast;

    const int t    = threadIdx.x;
    const int lane = t & 63;
    const int wid  = t >> 6;
    const int b    = blockIdx.x;

    // ---- deterministic compaction of correct set (each block redundantly) ----
    // thread t scans truth[t*32 .. t*32+32)
    const uint* tru32 = reinterpret_cast<const uint*>(truth);
    uint words[8];
#pragma unroll
    for (int q = 0; q < 8; ++q) words[q] = tru32[t * 8 + q];
    int cnt = 0;
#pragma unroll
    for (int q = 0; q < 8; ++q) {
        uint w = words[q];
        cnt += (w & 0xffu ? 1 : 0) + ((w >> 8) & 0xffu ? 1 : 0)
             + ((w >> 16) & 0xffu ? 1 : 0) + ((w >> 24) & 0xffu ? 1 : 0);
    }
    // inclusive scan within wave
    int inc = cnt;
#pragma unroll
    for (int d = 1; d < 64; d <<= 1) {
        int n = __shfl_up(inc, d, 64);
        if (lane >= d) inc += n;
    }
    if (lane == 63) wsum[wid] = inc;
    __syncthreads();
    int woff = 0;
    for (int w = 0; w < wid; ++w) woff += wsum[w];
    int slot = woff + inc - cnt;           // exclusive prefix
    if (t == 255) sK = woff + inc;
    // ordered writes (ascending j)
#pragma unroll
    for (int q = 0; q < 8; ++q) {
        uint w = words[q];
#pragma unroll
        for (int byte = 0; byte < 4; ++byte) {
            if ((w >> (byte * 8)) & 0xffu) {
                cconf[slot++] = conf[t * 32 + q * 4 + byte];
            }
        }
    }
    __syncthreads();
    const int K = sK;

    // ---- penalty: one i per thread, inner loop over K correct entries ----
    const int i = b * 256 + t;
    const float ci = conf[i];
    float acc = 0.0f;
    if (!truth[i]) {
        for (int s = 0; s < K; ++s) {
            const float d = ci - cconf[s];
            if (d > 0.0f) acc += d * d;
        }
    }
#pragma unroll
    for (int off = 32; off > 0; off >>= 1) acc += __shfl_xor(acc, off, 64);
    if (lane == 0) sred[wid] = acc;

    // ---- this block's ce_part slice (64 entries) ----
    float ce = (t < 64) ? ce_part[b * 64 + t] : 0.0f;
    if (wid == 0) {
#pragma unroll
        for (int off = 32; off > 0; off >>= 1) ce += __shfl_xor(ce, off, 64);
        if (lane == 0) cred[0] = ce;
    }
    __syncthreads();
    if (t == 0) {
        pen_sub[b] = sred[0] + sred[1] + sred[2] + sred[3];
        ce_sub[b]  = cred[0];
        __threadfence();
        int c = atomicAdd(counter, 1);
        isLast = (c == PEN_BLOCKS - 1) ? 1 : 0;
    }
    __syncthreads();

    // ---- last block does the final 32-way combine ----
    if (isLast && wid == 0) {
        __threadfence();
        float cs = (lane < PEN_BLOCKS) ? ce_sub[lane]  : 0.0f;
        float ps = (lane < PEN_BLOCKS) ? pen_sub[lane] : 0.0f;
#pragma unroll
        for (int off = 32; off > 0; off >>= 1) {
            cs += __shfl_xor(cs, off, 64);
            ps += __shfl_xor(ps, off, 64);
        }
        if (lane == 0) out[0] = cs * (1.0f / (float)NROWS) + LAMBDA_P * ps;
    }
}

extern "C" void kernel_launch(void* const* d_in, const int* in_sizes, int n_in,
                              void* d_out, int out_size, void* d_ws, size_t ws_size,
                              hipStream_t stream) {
    const float* outputs = (const float*)d_in[0];
    const float* conf    = (const float*)d_in[1];
    const int*   labels  = (const int*)d_in[2];
    float* out = (float*)d_out;

    float*         ce_part = (float*)d_ws;
    float*         ce_sub  = (float*)((char*)d_ws + 8192);
    float*         pen_sub = (float*)((char*)d_ws + 8320);
    int*           counter = (int*)((char*)d_ws + 8448);
    unsigned char* truth   = (unsigned char*)((char*)d_ws + 8704);

    row_pass_k<<<CE_BLOCKS, 256, 0, stream>>>(outputs, labels, ce_part, truth, counter);
    penalty_fin_k<<<PEN_BLOCKS, 256, 0, stream>>>(conf, truth, ce_part,
                                                  ce_sub, pen_sub, counter, out);
}